// Round 1
// 182.852 us; speedup vs baseline: 1.1775x; 1.1775x over previous
//
#include <hip/hip_runtime.h>
#include <hip/hip_bf16.h>

typedef _Float16 half8_t __attribute__((ext_vector_type(8)));
typedef _Float16 half4_t __attribute__((ext_vector_type(4)));
typedef float    f32x4  __attribute__((ext_vector_type(4)));

#define MFMA32(a, b, c) __builtin_amdgcn_mfma_f32_16x16x32_f16((a), (b), (c), 0, 0, 0)
#define MFMA16(a, b, c) __builtin_amdgcn_mfma_f32_16x16x16f16((a), (b), (c), 0, 0, 0)

// async global->LDS DMA, 16B per lane: LDS dst = base + lane*16 (HW rule)
__device__ __forceinline__ void load_lds16(const void* g, void* l) {
    __builtin_amdgcn_global_load_lds(
        (const __attribute__((address_space(1))) unsigned int*)g,
        (__attribute__((address_space(3))) unsigned int*)l, 16, 0, 0);
}

// ---------------------------------------------------------------------------
// Kernel 1: UGRNN recurrence on MFMA, operand-SWAPPED so no transpose is ever
// needed. We compute D^T = W^T X^T: A = weight fragment, B = activations.
// For 16x16x16 f16 MFMA the B layout is B[k=4q+i][n=t16] == the C/D layout
// [4q+r][t16], so each step's f32 state packs directly into the next step's
// B fragment: per step = 8 cvt + 5 MFMA + activation math. Zero LDS traffic,
// zero cross-lane ops, zero lgkm drains inside the recurrence.
// One wave = two 16-token tiles (32 tokens, b fixed).
// Gates: pre = MFMA16(Ug, h, MFMA16(Wg, x, bias))  (chained via C operand).
// State layout: [unit=4q+r][token=t16]; final store = coalesced half4.
// ---------------------------------------------------------------------------
__global__
__attribute__((amdgpu_flat_work_group_size(256, 256)))
void ugrnn_mfma(
    const float* __restrict__ inputs,
    const float* __restrict__ Wn, const float* __restrict__ Wg,
    const float* __restrict__ Ug, const float* __restrict__ bg,
    const float* __restrict__ Wc, const float* __restrict__ Uc,
    const float* __restrict__ bc, const float* __restrict__ We,
    const float* __restrict__ be, _Float16* __restrict__ h_t)
{
    __shared__ float raw[4][2 * 544];

    const int wave = threadIdx.x >> 6;
    const int lane = threadIdx.x & 63;
    const int t16  = lane & 15;
    const int q    = lane >> 4;

    const int pair = blockIdx.x * 4 + wave;
    const int b    = pair >> 7;
    const int n0   = (pair & 127) << 5;

    // coalesced stage of this wave's 32 input rows (34 f32 each) into LDS
    const float* gsrc = inputs + ((size_t)b * 4096 + n0) * 34;
    float* rw = raw[wave];
#pragma unroll
    for (int r = 0; r < 17; ++r) rw[r * 64 + lane] = gsrc[r * 64 + lane];

    // weight A-fragments (A[m=t16][k] = W[k][t16], i.e. W^T)
    half8_t An;                       // Wn: K=32
#pragma unroll
    for (int i = 0; i < 8; ++i)
        An[i] = (_Float16)Wn[(q * 8 + i) * 16 + t16];

    half4_t Awg, Aug, Awc, Auc, Awe;  // K=16 frags: A[m=t16][k=4q+i]
#pragma unroll
    for (int i = 0; i < 4; ++i) {
        const int k = 4 * q + i;
        Awg[i] = (_Float16)Wg[k * 16 + t16];
        Aug[i] = (_Float16)Ug[k * 16 + t16];
        Awc[i] = (_Float16)Wc[k * 16 + t16];
        Auc[i] = (_Float16)Uc[k * 16 + t16];
        Awe[i] = (_Float16)We[k * 16 + t16];
    }
    // biases: D rows are units 4q+r
    f32x4 bgC, bcC, beC;
#pragma unroll
    for (int r = 0; r < 4; ++r) {
        bgC[r] = bg[4 * q + r];
        bcC[r] = bc[4 * q + r];
        beC[r] = be[4 * q + r];
    }

    f32x4 m[2], h[2], e[2];
    const f32x4 zc = {0.f, 0.f, 0.f, 0.f};
#pragma unroll
    for (int u2 = 0; u2 < 2; ++u2) {
        const float* rt = rw + u2 * 544;
        half8_t Bx;                   // B[k=8q+i][n=t16] = neigh[t16][8q+i]
#pragma unroll
        for (int i = 0; i < 8; ++i)
            Bx[i] = (_Float16)rt[t16 * 34 + 1 + q * 8 + i];
        m[u2] = MFMA32(An, Bx, zc);
        const float h0 = rt[t16 * 34 + 0];   // broadcast over units
        const float e0 = rt[t16 * 34 + 33];
        h[u2] = (f32x4){h0, h0, h0, h0};
        e[u2] = (f32x4){e0, e0, e0, e0};
    }

#pragma unroll 1
    for (int step = 0; step < 8; ++step) {
        f32x4 gp[2], cp[2], ep[2];
#pragma unroll
        for (int u2 = 0; u2 < 2; ++u2) {
            const f32x4 x = m[u2] + e[u2];
            half4_t xB, hB;           // B[k=4q+r][n=t16] == D layout: direct!
#pragma unroll
            for (int r = 0; r < 4; ++r) {
                xB[r] = (_Float16)x[r];
                hB[r] = (_Float16)h[u2][r];
            }
            gp[u2] = MFMA16(Aug, hB, MFMA16(Awg, xB, bgC));
            cp[u2] = MFMA16(Auc, hB, MFMA16(Awc, xB, bcC));
            if (step < 7) ep[u2] = MFMA16(Awe, xB, beC);
        }
#pragma unroll
        for (int u2 = 0; u2 < 2; ++u2) {
#pragma unroll
            for (int r = 0; r < 4; ++r) {
                float gv = __builtin_amdgcn_rcpf(1.0f + __expf(-gp[u2][r]));
                float cv = 1.0f - 2.0f * __builtin_amdgcn_rcpf(1.0f + __expf(2.0f * cp[u2][r]));
                h[u2][r] = cv + gv * (h[u2][r] - cv);
                if (step < 7)
                    e[u2][r] = 1.0f - 2.0f * __builtin_amdgcn_rcpf(1.0f + __expf(2.0f * ep[u2][r]));
            }
        }
    }

    // store: h_t[b][n = n0+u2*16+t16][u = 4q..4q+3] -> one 8B store per tile,
    // 64 lanes tile 512B contiguously per u2
#pragma unroll
    for (int u2 = 0; u2 < 2; ++u2) {
        half4_t hv;
#pragma unroll
        for (int r = 0; r < 4; ++r) hv[r] = (_Float16)h[u2][r];
        *(half4_t*)(h_t + (size_t)b * 65536
                        + (size_t)(n0 + u2 * 16 + t16) * 16 + 4 * q) = hv;
    }
}

// ---------------------------------------------------------------------------
// Kernel 2: FC1 partial GEMM, DMA-pipelined. (unchanged this round)
// ---------------------------------------------------------------------------
__global__
__attribute__((amdgpu_flat_work_group_size(256, 256), amdgpu_waves_per_eu(1, 2)))
void fc1_mfma(const _Float16* __restrict__ h_t, const float* __restrict__ W1,
              _Float16* __restrict__ partials)
{
    __shared__ float w1s[2][64][258];         // 132096 B
    const int tid  = threadIdx.x;
    const int wave = tid >> 6;
    const int lane = tid & 63;
    const int t16  = lane & 15;
    const int q    = lane >> 4;
    const int i0   = blockIdx.x * 256;

    f32x4 acc[4][4];
#pragma unroll
    for (int mt = 0; mt < 4; ++mt)
#pragma unroll
        for (int nt = 0; nt < 4; ++nt)
            acc[mt][nt] = (f32x4){0.f, 0.f, 0.f, 0.f};

#pragma unroll
    for (int r = 0; r < 16; ++r) {
        int row = wave * 16 + r;
        load_lds16(W1 + (size_t)(i0 + row) * 256 + lane * 4, &w1s[0][row][0]);
    }
    __syncthreads();                           // drains chunk-0 DMA

#pragma unroll 1
    for (int c = 0; c < 4; ++c) {
        const int buf = c & 1;
        const int cb  = i0 + c * 64;

        half8_t A[2][4];
#pragma unroll
        for (int ks = 0; ks < 2; ++ks)
#pragma unroll
            for (int mt = 0; mt < 4; ++mt)
                A[ks][mt] = *(const half8_t*)(h_t
                    + (size_t)(mt * 16 + t16) * 65536 + cb + ks * 32 + q * 8);

        if (c < 3) {
#pragma unroll
            for (int r = 0; r < 16; ++r) {
                int row = wave * 16 + r;
                load_lds16(W1 + (size_t)(cb + 64 + row) * 256 + lane * 4,
                           &w1s[buf ^ 1][row][0]);
            }
        }

#pragma unroll
        for (int ks = 0; ks < 2; ++ks) {
#pragma unroll
            for (int nt = 0; nt < 4; ++nt) {
                int j = (wave * 4 + nt) * 16 + t16;
                half8_t Bf;
#pragma unroll
                for (int i = 0; i < 8; ++i)
                    Bf[i] = (_Float16)w1s[buf][ks * 32 + q * 8 + i][j];
#pragma unroll
                for (int mt = 0; mt < 4; ++mt)
                    acc[mt][nt] = MFMA32(A[ks][mt], Bf, acc[mt][nt]);
            }
        }
        __syncthreads();                       // sync + drain next-chunk DMA
    }

    _Float16* pb = partials + (size_t)blockIdx.x * 16384;
#pragma unroll
    for (int mt = 0; mt < 4; ++mt)
#pragma unroll
        for (int nt = 0; nt < 4; ++nt)
#pragma unroll
            for (int r = 0; r < 4; ++r)
                pb[(mt * 16 + 4 * q + r) * 256 + (wave * 4 + nt) * 16 + t16] =
                    (_Float16)acc[mt][nt][r];
}

// ---------------------------------------------------------------------------
// Kernel 3: fused partial-reduce + bias + tail MLP + softmax.
// Widened to 1024 threads: phase-1 K-reduction split 4-way (quarter the
// serial load chain, 4x loads in flight), phase-2 split 32-way.
// ---------------------------------------------------------------------------
__global__ __launch_bounds__(1024) void mlp_tail(
    const _Float16* __restrict__ partials, const float* __restrict__ b1,
    const float* __restrict__ W2, const float* __restrict__ b2,
    const float* __restrict__ W3, const float* __restrict__ b3,
    float* __restrict__ out)
{
    __shared__ float x1p[4][256];
    __shared__ float x1s[256];
    __shared__ float x2q[32][33];
    __shared__ float x2s[32];
    __shared__ float lg[2];
    const int b = blockIdx.x, tid = threadIdx.x;
    const int j = tid & 255, kg = tid >> 8;

    const _Float16* p = partials + (size_t)(kg * 64) * 16384 + (size_t)b * 256 + j;
    float s0 = 0.f, s1 = 0.f, s2 = 0.f, s3 = 0.f;
#pragma unroll 4
    for (int k = 0; k < 64; k += 4) {
        s0 += (float)p[(size_t)(k + 0) * 16384];
        s1 += (float)p[(size_t)(k + 1) * 16384];
        s2 += (float)p[(size_t)(k + 2) * 16384];
        s3 += (float)p[(size_t)(k + 3) * 16384];
    }
    x1p[kg][j] = s0 + s1 + s2 + s3;
    __syncthreads();
    if (tid < 256)
        x1s[j] = fmaxf(b1[j] + x1p[0][j] + x1p[1][j] + x1p[2][j] + x1p[3][j], 0.f);
    __syncthreads();

    const int j2 = tid & 31, g2 = tid >> 5;
    float s = 0.f;
#pragma unroll
    for (int k = g2 * 8; k < g2 * 8 + 8; ++k) s += x1s[k] * W2[k * 32 + j2];
    x2q[g2][j2] = s;
    __syncthreads();
    if (tid < 32) {
        float t = b2[tid];
#pragma unroll
        for (int g = 0; g < 32; ++g) t += x2q[g][tid];
        x2s[tid] = fmaxf(t, 0.f);
    }
    __syncthreads();
    if (tid < 2) {
        float t = b3[tid];
#pragma unroll
        for (int k = 0; k < 32; ++k) t += x2s[k] * W3[k * 2 + tid];
        lg[tid] = t;
    }
    __syncthreads();
    if (tid == 0) {
        float mx = fmaxf(lg[0], lg[1]);
        float e0 = __expf(lg[0] - mx), e1 = __expf(lg[1] - mx);
        float inv = 1.0f / (e0 + e1);
        out[b * 2 + 0] = e0 * inv;
        out[b * 2 + 1] = e1 * inv;
    }
}

// ---------------------------------------------------------------------------
extern "C" void kernel_launch(void* const* d_in, const int* in_sizes, int n_in,
                              void* d_out, int out_size, void* d_ws, size_t ws_size,
                              hipStream_t stream) {
    const float* inputs = (const float*)d_in[0];
    const float* Wn = (const float*)d_in[1];
    const float* Wg = (const float*)d_in[2];
    const float* Ug = (const float*)d_in[3];
    const float* bg = (const float*)d_in[4];
    const float* Wc = (const float*)d_in[5];
    const float* Uc = (const float*)d_in[6];
    const float* bc = (const float*)d_in[7];
    const float* We = (const float*)d_in[8];
    const float* be = (const float*)d_in[9];
    const float* W1 = (const float*)d_in[10];
    const float* b1 = (const float*)d_in[11];
    const float* W2 = (const float*)d_in[12];
    const float* b2 = (const float*)d_in[13];
    const float* W3 = (const float*)d_in[14];
    const float* b3 = (const float*)d_in[15];
    float* out = (float*)d_out;

    // ws: h_t f16 [64][65536] = 8 MB; partials f16 [256][64][256] = 8 MB
    _Float16* h_t      = (_Float16*)d_ws;
    _Float16* partials = (_Float16*)((char*)d_ws + (size_t)64 * 65536 * 2);

    ugrnn_mfma<<<2048, 256, 0, stream>>>(inputs, Wn, Wg, Ug, bg, Wc, Uc, bc,
                                         We, be, h_t);
    fc1_mfma<<<256, 256, 0, stream>>>(h_t, W1, partials);
    mlp_tail<<<64, 1024, 0, stream>>>(partials, b1, W2, b2, W3, b3, out);
}